// Round 11
// baseline (62.576 us; speedup 1.0000x reference)
//
#include <hip/hip_runtime.h>
#include <cstdint>
#include <cstddef>

#define SEQD 20
#define HID  512
#define LSEQ 2048
#define MROWS 8192
#define GBM 128
#define GBN 128
#define GBK 64
// Hpart layout: [slice=4][q=7][8192] f32, planes contiguous per (slice,q).
// q: 0..2 = ss logits, 3..4 = angles, 5 = ci, 6 = cj. No zeroing needed:
// every slot is written exactly once (slice=xblk, rows by yblk). No atomics.

typedef __attribute__((ext_vector_type(4))) float f32x4;
typedef __attribute__((ext_vector_type(8))) short bf16x8;

__device__ __forceinline__ ushort f2bf(float f) {
  union { float f; unsigned u; } v; v.f = f;
  unsigned r = v.u + 0x7fffu + ((v.u >> 16) & 1u);   // RNE
  return (ushort)(r >> 16);
}
// XOR-swizzle of byte offset b (0..127) within a 128B k-stripe, keyed by row.
// Involution on 16B-slot bits (4..6). Written and read with the same XOR.
__device__ __forceinline__ int swzb(int row, int b) {
  return (b & 0x0F) | ((b ^ ((row & 7) << 4)) & 0x70);
}

// ===========================================================================
// Kernel 1: fully self-contained gemm + heads. Each block:
//  - stages X rows (bm..bm+127) to LDS once,
//  - per K-step COMPUTES its A-tile h1[128][64] = relu(X@W1+b1) -> bf16 LDS
//    (4x recompute across xblk; ~670 MFLOP total, VALU pipe),
//  - per K-step stages its B-tile from W2 (coalesced L2 reads) with an
//    in-register 8x4 micro-transpose -> [n][k] swizzled bf16 LDS,
//  - MFMA loop + head-partial epilogue identical to the R7-proven kernel,
//  - writes Hpart[xblk][q][bm..bm+127] (coalesced, non-atomic).
// Deletes: prep kernel, one launch gap, h1/W2t global round-trips, atomics.
// ===========================================================================
__global__ __launch_bounds__(256) void k_gemm_all(
    const float* __restrict__ X,   const float* __restrict__ W1,
    const float* __restrict__ b1,  const float* __restrict__ W2,
    const float* __restrict__ b2,  const float* __restrict__ Wss,
    const float* __restrict__ Wang,const float* __restrict__ Wc,
    float* __restrict__ Hpart) {
  __shared__ ushort As[2][GBM * GBK];   // 2 x 16 KB, [m][k] swizzled
  __shared__ ushort Bs[2][GBM * GBK];   // 2 x 16 KB, [n][k] swizzled
  __shared__ float  Xs[SEQD][GBM];      // 10.24 KB, [k][row]
  const int t = threadIdx.x;
  const int wave = t >> 6, lane = t & 63;
  const int l15 = lane & 15, lhi = lane >> 4;
  const int wr = wave >> 1, wc = wave & 1;
  const int swz = (blockIdx.x & 7) * 32 + (blockIdx.x >> 3);  // bijective XCD
  const int xblk = swz & 3, yblk = swz >> 2;
  const int bm = yblk * GBM, bn = xblk * GBN;

  // ---- stage X rows bm..bm+127 into Xs[k][row] (one-time, coalesced) ----
  for (int i = t; i < GBM * SEQD; i += 256)
    Xs[i % SEQD][i / SEQD] = X[(size_t)bm * SEQD + i];
  __syncthreads();

  // A-compute mapping: 4 rows x 8 cols per thread
  const int tcol = (t & 7) * 8;        // 0..56
  const int trow = (t >> 3) * 4;       // 0..124
  // B-stage mapping: 4 n (stride 32) x 8 k per thread
  const int bnc = t & 31;              // n within 32-group
  const int bkr = (t >> 5) * 8;        // k0 within 64

  f32x4 acc[4][4];
#pragma unroll
  for (int mi = 0; mi < 4; ++mi)
#pragma unroll
    for (int ni = 0; ni < 4; ++ni) acc[mi][ni] = {0.f, 0.f, 0.f, 0.f};

#define PRODUCE(buf, kt)                                                       \
  {                                                                            \
    const int c0 = (kt) * GBK;                                                 \
    /* A: compute h1 rows trow..+3, cols c0+tcol..+7 */                        \
    float aR[4][8];                                                            \
    {                                                                          \
      const float4 bb0 = *(const float4*)&b1[c0 + tcol];                       \
      const float4 bb1 = *(const float4*)&b1[c0 + tcol + 4];                   \
      _Pragma("unroll")                                                        \
      for (int r = 0; r < 4; ++r) {                                            \
        aR[r][0] = bb0.x; aR[r][1] = bb0.y; aR[r][2] = bb0.z; aR[r][3] = bb0.w;\
        aR[r][4] = bb1.x; aR[r][5] = bb1.y; aR[r][6] = bb1.z; aR[r][7] = bb1.w;\
      }                                                                        \
      _Pragma("unroll")                                                        \
      for (int k = 0; k < SEQD; ++k) {                                         \
        const float4 w0 = *(const float4*)&W1[k * HID + c0 + tcol];            \
        const float4 w1 = *(const float4*)&W1[k * HID + c0 + tcol + 4];        \
        const float4 xr = *(const float4*)&Xs[k][trow];                        \
        const float xv[4] = {xr.x, xr.y, xr.z, xr.w};                          \
        _Pragma("unroll")                                                      \
        for (int r = 0; r < 4; ++r) {                                          \
          aR[r][0] += xv[r] * w0.x; aR[r][1] += xv[r] * w0.y;                  \
          aR[r][2] += xv[r] * w0.z; aR[r][3] += xv[r] * w0.w;                  \
          aR[r][4] += xv[r] * w1.x; aR[r][5] += xv[r] * w1.y;                  \
          aR[r][6] += xv[r] * w1.z; aR[r][7] += xv[r] * w1.w;                  \
        }                                                                      \
      }                                                                        \
      _Pragma("unroll")                                                        \
      for (int r = 0; r < 4; ++r) {                                            \
        bf16x8 o;                                                              \
        _Pragma("unroll")                                                      \
        for (int c = 0; c < 8; ++c)                                            \
          o[c] = (short)f2bf(fmaxf(aR[r][c], 0.f));                            \
        const int row = trow + r;                                              \
        *(bf16x8*)&As[buf][(row * 128 + swzb(row, tcol * 2)) >> 1] = o;        \
      }                                                                        \
    }                                                                          \
    /* B: W2[k][n] -> Bs[n][k] bf16, 8k x 4n micro-transpose in regs */        \
    {                                                                          \
      float v[4][8];                                                           \
      _Pragma("unroll")                                                        \
      for (int i = 0; i < 8; ++i) {                                            \
        const float* wrp = &W2[(size_t)(c0 + bkr + i) * HID + bn + bnc];       \
        v[0][i] = wrp[0];  v[1][i] = wrp[32];                                  \
        v[2][i] = wrp[64]; v[3][i] = wrp[96];                                  \
      }                                                                        \
      _Pragma("unroll")                                                        \
      for (int q = 0; q < 4; ++q) {                                            \
        bf16x8 o;                                                              \
        _Pragma("unroll")                                                      \
        for (int i = 0; i < 8; ++i) o[i] = (short)f2bf(v[q][i]);               \
        const int n = q * 32 + bnc;                                            \
        *(bf16x8*)&Bs[buf][(n * 128 + swzb(n, bkr * 2)) >> 1] = o;             \
      }                                                                        \
    }                                                                          \
  }

#define COMPUTE(buf)                                                           \
  {                                                                            \
    _Pragma("unroll")                                                          \
    for (int kk = 0; kk < 2; ++kk) {                                           \
      bf16x8 af[4], bff[4];                                                    \
      _Pragma("unroll")                                                        \
      for (int mi = 0; mi < 4; ++mi) {                                         \
        const int row = wr * 64 + mi * 16 + l15;                               \
        af[mi] = *(const bf16x8*)&As[buf][(row * 128 + swzb(row, kk * 64 + lhi * 16)) >> 1]; \
      }                                                                        \
      _Pragma("unroll")                                                        \
      for (int ni = 0; ni < 4; ++ni) {                                         \
        const int rn = wc * 64 + ni * 16 + l15;                                \
        bff[ni] = *(const bf16x8*)&Bs[buf][(rn * 128 + swzb(rn, kk * 64 + lhi * 16)) >> 1]; \
      }                                                                        \
      _Pragma("unroll")                                                        \
      for (int mi = 0; mi < 4; ++mi)                                           \
        _Pragma("unroll")                                                      \
        for (int ni = 0; ni < 4; ++ni)                                         \
          acc[mi][ni] = __builtin_amdgcn_mfma_f32_16x16x32_bf16(af[mi], bff[ni], acc[mi][ni], 0, 0, 0); \
    }                                                                          \
  }

  PRODUCE(0, 0)
  __syncthreads();
#pragma unroll 1
  for (int kt = 0; kt < 8; ++kt) {
    if (kt < 7) PRODUCE((kt + 1) & 1, kt + 1)
    COMPUTE(kt & 1)
    __syncthreads();   // buf(kt) reads done; buf(kt+1) writes visible
  }

  // ---- epilogue: bias+relu, head partials, 16-lane reduce, wc-combine ----
  // comb[2][128][8] aliases Bs[0] (dead after the final barrier).
  float* combp = (float*)(&Bs[0][0]);
  float bias[4], ws0[4], ws1[4], ws2[4], wa0[4], wa1[4], wc0[4], wc1[4];
#pragma unroll
  for (int ni = 0; ni < 4; ++ni) {
    const int col = bn + wc * 64 + ni * 16 + l15;
    bias[ni] = b2[col];
    ws0[ni] = Wss[col * 3 + 0]; ws1[ni] = Wss[col * 3 + 1]; ws2[ni] = Wss[col * 3 + 2];
    wa0[ni] = Wang[col * 2 + 0]; wa1[ni] = Wang[col * 2 + 1];
    wc0[ni] = Wc[col]; wc1[ni] = Wc[HID + col];
  }
#pragma unroll
  for (int mi = 0; mi < 4; ++mi) {
#pragma unroll
    for (int j = 0; j < 4; ++j) {
      float p0 = 0, p1 = 0, p2 = 0, p3 = 0, p4 = 0, p5 = 0, p6 = 0;
#pragma unroll
      for (int ni = 0; ni < 4; ++ni) {
        const float v = fmaxf(acc[mi][ni][j] + bias[ni], 0.f);
        p0 += v * ws0[ni]; p1 += v * ws1[ni]; p2 += v * ws2[ni];
        p3 += v * wa0[ni]; p4 += v * wa1[ni];
        p5 += v * wc0[ni]; p6 += v * wc1[ni];
      }
#pragma unroll
      for (int m = 1; m <= 8; m <<= 1) {
        p0 += __shfl_xor(p0, m); p1 += __shfl_xor(p1, m); p2 += __shfl_xor(p2, m);
        p3 += __shfl_xor(p3, m); p4 += __shfl_xor(p4, m);
        p5 += __shfl_xor(p5, m); p6 += __shfl_xor(p6, m);
      }
      if (l15 == 0) {
        const int lr = wr * 64 + mi * 16 + lhi * 4 + j;   // local row 0..127
        float* cp = &combp[((size_t)wc * GBM + lr) * 8];
        cp[0] = p0; cp[1] = p1; cp[2] = p2; cp[3] = p3;
        cp[4] = p4; cp[5] = p5; cp[6] = p6;
      }
    }
  }
  __syncthreads();
  if (t < GBM) {
#pragma unroll
    for (int q = 0; q < 7; ++q) {
      const float val = combp[(size_t)t * 8 + q] + combp[((size_t)GBM + t) * 8 + q];
      Hpart[((size_t)(xblk * 7 + q)) * MROWS + bm + t] = val;   // coalesced
    }
  }
#undef PRODUCE
#undef COMPUTE
}

// ===========================================================================
// Kernel 2: finalize + contact. Grid 1024 = 4 batches x 256 tiles of 8 rows.
// cj plane reads are CONTIGUOUS (plane layout), float4-coalesced.
// ===========================================================================
__global__ __launch_bounds__(256) void k_fc(const float* __restrict__ Hpart,
                                            const float* __restrict__ bss,
                                            const float* __restrict__ bang,
                                            const float* __restrict__ bc,
                                            float* __restrict__ ssO,
                                            float* __restrict__ angO,
                                            float* __restrict__ contact) {
  __shared__ float cj_l[LSEQ];
  __shared__ float ci_l[8];
  const int blk = blockIdx.x;
  const int b   = blk >> 8;
  const int i0  = (blk & 255) * 8;
  const int t   = threadIdx.x;
  const size_t rowbase = (size_t)b * LSEQ;

  {
    const float* p0 = Hpart + (size_t)(0 * 7 + 6) * MROWS + rowbase;
    const float* p1 = Hpart + (size_t)(1 * 7 + 6) * MROWS + rowbase;
    const float* p2 = Hpart + (size_t)(2 * 7 + 6) * MROWS + rowbase;
    const float* p3 = Hpart + (size_t)(3 * 7 + 6) * MROWS + rowbase;
#pragma unroll
    for (int it = 0; it < 2; ++it) {
      const int j = it * 1024 + t * 4;
      const float4 a = *(const float4*)&p0[j];
      const float4 bq = *(const float4*)&p1[j];
      const float4 c = *(const float4*)&p2[j];
      const float4 d = *(const float4*)&p3[j];
      float4 s;
      s.x = a.x + bq.x + c.x + d.x;
      s.y = a.y + bq.y + c.y + d.y;
      s.z = a.z + bq.z + c.z + d.z;
      s.w = a.w + bq.w + c.w + d.w;
      *(float4*)&cj_l[j] = s;
    }
  }
  if (t < 8) {
    const size_t r = rowbase + i0 + t;
    float q[6] = {0, 0, 0, 0, 0, 0};
#pragma unroll
    for (int s = 0; s < 4; ++s)
#pragma unroll
      for (int qq = 0; qq < 6; ++qq)
        q[qq] += Hpart[(size_t)(s * 7 + qq) * MROWS + r];
    const float l0 = q[0] + bss[0], l1 = q[1] + bss[1], l2 = q[2] + bss[2];
    const float mx = fmaxf(l0, fmaxf(l1, l2));
    const float e0 = __expf(l0 - mx), e1 = __expf(l1 - mx), e2 = __expf(l2 - mx);
    const float inv = 1.f / (e0 + e1 + e2);
    ssO[r * 3 + 0] = e0 * inv;
    ssO[r * 3 + 1] = e1 * inv;
    ssO[r * 3 + 2] = e2 * inv;
    angO[r * 2 + 0] = q[3] + bang[0];
    angO[r * 2 + 1] = q[4] + bang[1];
    ci_l[t] = q[5] + bc[0];
  }
  __syncthreads();

#pragma unroll
  for (int r = 0; r < 8; ++r) {
    const float base = ci_l[r];
    float* orow = contact + (rowbase + i0 + r) * LSEQ;
#pragma unroll
    for (int jc = 0; jc < 2; ++jc) {
      const int j0 = jc * 1024 + t * 4;
      const float4 c4 = *(const float4*)&cj_l[j0];
      float4 o;
      o.x = 1.f / (1.f + __expf(-(base + c4.x)));
      o.y = 1.f / (1.f + __expf(-(base + c4.y)));
      o.z = 1.f / (1.f + __expf(-(base + c4.z)));
      o.w = 1.f / (1.f + __expf(-(base + c4.w)));
      *(float4*)&orow[j0] = o;
    }
  }
}

// ---------------------------------------------------------------------------
extern "C" void kernel_launch(void* const* d_in, const int* in_sizes, int n_in,
                              void* d_out, int out_size, void* d_ws, size_t ws_size,
                              hipStream_t stream) {
  const float* X    = (const float*)d_in[0];
  const float* W1   = (const float*)d_in[1];
  const float* b1   = (const float*)d_in[2];
  const float* W2   = (const float*)d_in[3];
  const float* b2   = (const float*)d_in[4];
  const float* Wss  = (const float*)d_in[5];
  const float* bss  = (const float*)d_in[6];
  const float* Wang = (const float*)d_in[7];
  const float* bang = (const float*)d_in[8];
  const float* Wc   = (const float*)d_in[9];
  const float* bc   = (const float*)d_in[10];

  float* out     = (float*)d_out;
  float* ssO     = out;                         // [8192,3]
  float* angO    = out + 24576;                 // [8192,2]
  float* contact = out + 40960;                 // [4,2048,2048]

  float* Hpart = (float*)d_ws;                  // [4][7][8192] = 896 KB

  k_gemm_all<<<256, 256, 0, stream>>>(X, W1, b1, W2, b2, Wss, Wang, Wc, Hpart);
  k_fc<<<1024, 256, 0, stream>>>(Hpart, bss, bang, bc, ssO, angO, contact);
}

// Round 12
// 62.202 us; speedup vs baseline: 1.0060x; 1.0060x over previous
//
#include <hip/hip_runtime.h>
#include <cstdint>
#include <cstddef>

#define SEQD 20
#define HID  512
#define LSEQ 2048
#define MROWS 8192
#define GBM 128
#define GBN 128
#define GBK 64
// Hpart layout: [slice=4][q=7][8192] f32, planes contiguous per (slice,q).
// q: 0..2 = ss logits, 3..4 = angles, 5 = ci, 6 = cj. No zeroing needed:
// every slot is written exactly once (slice=xblk, rows by yblk). No atomics.

typedef __attribute__((ext_vector_type(4))) float f32x4;
typedef __attribute__((ext_vector_type(8))) short bf16x8;

__device__ __forceinline__ ushort f2bf(float f) {
  union { float f; unsigned u; } v; v.f = f;
  unsigned r = v.u + 0x7fffu + ((v.u >> 16) & 1u);   // RNE
  return (ushort)(r >> 16);
}
// XOR-swizzle of byte offset b (0..127) within a 128B k-stripe, keyed by row.
// Involution on 16B-slot bits (4..6). Written and read with the same XOR.
__device__ __forceinline__ int swzb(int row, int b) {
  return (b & 0x0F) | ((b ^ ((row & 7) << 4)) & 0x70);
}

// ===========================================================================
// Kernel 1: fully self-contained gemm + heads. Each block:
//  - stages X rows (bm..bm+127) to LDS once,
//  - per K-step COMPUTES its A-tile h1[128][64] = relu(X@W1+b1) -> bf16 LDS
//    (4x recompute across xblk; ~670 MFLOP total, VALU pipe),
//  - per K-step stages its B-tile from W2 (coalesced L2 reads) with an
//    in-register 8x4 micro-transpose -> [n][k] swizzled bf16 LDS,
//  - MFMA loop + head-partial epilogue identical to the R7-proven kernel,
//  - writes Hpart[xblk][q][bm..bm+127] (coalesced, non-atomic).
// Deletes: prep kernel, one launch gap, h1/W2t global round-trips, atomics.
// ===========================================================================
__global__ __launch_bounds__(256) void k_gemm_all(
    const float* __restrict__ X,   const float* __restrict__ W1,
    const float* __restrict__ b1,  const float* __restrict__ W2,
    const float* __restrict__ b2,  const float* __restrict__ Wss,
    const float* __restrict__ Wang,const float* __restrict__ Wc,
    float* __restrict__ Hpart) {
  __shared__ ushort As[2][GBM * GBK];   // 2 x 16 KB, [m][k] swizzled
  __shared__ ushort Bs[2][GBM * GBK];   // 2 x 16 KB, [n][k] swizzled
  __shared__ float  Xs[SEQD][GBM];      // 10.24 KB, [k][row]
  const int t = threadIdx.x;
  const int wave = t >> 6, lane = t & 63;
  const int l15 = lane & 15, lhi = lane >> 4;
  const int wr = wave >> 1, wc = wave & 1;
  const int swz = (blockIdx.x & 7) * 32 + (blockIdx.x >> 3);  // bijective XCD
  const int xblk = swz & 3, yblk = swz >> 2;
  const int bm = yblk * GBM, bn = xblk * GBN;

  // ---- stage X rows bm..bm+127 into Xs[k][row] (one-time, coalesced) ----
  for (int i = t; i < GBM * SEQD; i += 256)
    Xs[i % SEQD][i / SEQD] = X[(size_t)bm * SEQD + i];
  __syncthreads();

  // A-compute mapping: 4 rows x 8 cols per thread
  const int tcol = (t & 7) * 8;        // 0..56
  const int trow = (t >> 3) * 4;       // 0..124
  // B-stage mapping: 4 n (stride 32) x 8 k per thread
  const int bnc = t & 31;              // n within 32-group
  const int bkr = (t >> 5) * 8;        // k0 within 64

  f32x4 acc[4][4];
#pragma unroll
  for (int mi = 0; mi < 4; ++mi)
#pragma unroll
    for (int ni = 0; ni < 4; ++ni) acc[mi][ni] = {0.f, 0.f, 0.f, 0.f};

#define PRODUCE(buf, kt)                                                       \
  {                                                                            \
    const int c0 = (kt) * GBK;                                                 \
    /* A: compute h1 rows trow..+3, cols c0+tcol..+7 */                        \
    float aR[4][8];                                                            \
    {                                                                          \
      const float4 bb0 = *(const float4*)&b1[c0 + tcol];                       \
      const float4 bb1 = *(const float4*)&b1[c0 + tcol + 4];                   \
      _Pragma("unroll")                                                        \
      for (int r = 0; r < 4; ++r) {                                            \
        aR[r][0] = bb0.x; aR[r][1] = bb0.y; aR[r][2] = bb0.z; aR[r][3] = bb0.w;\
        aR[r][4] = bb1.x; aR[r][5] = bb1.y; aR[r][6] = bb1.z; aR[r][7] = bb1.w;\
      }                                                                        \
      _Pragma("unroll")                                                        \
      for (int k = 0; k < SEQD; ++k) {                                         \
        const float4 w0 = *(const float4*)&W1[k * HID + c0 + tcol];            \
        const float4 w1 = *(const float4*)&W1[k * HID + c0 + tcol + 4];        \
        const float4 xr = *(const float4*)&Xs[k][trow];                        \
        const float xv[4] = {xr.x, xr.y, xr.z, xr.w};                          \
        _Pragma("unroll")                                                      \
        for (int r = 0; r < 4; ++r) {                                          \
          aR[r][0] += xv[r] * w0.x; aR[r][1] += xv[r] * w0.y;                  \
          aR[r][2] += xv[r] * w0.z; aR[r][3] += xv[r] * w0.w;                  \
          aR[r][4] += xv[r] * w1.x; aR[r][5] += xv[r] * w1.y;                  \
          aR[r][6] += xv[r] * w1.z; aR[r][7] += xv[r] * w1.w;                  \
        }                                                                      \
      }                                                                        \
      _Pragma("unroll")                                                        \
      for (int r = 0; r < 4; ++r) {                                            \
        bf16x8 o;                                                              \
        _Pragma("unroll")                                                      \
        for (int c = 0; c < 8; ++c)                                            \
          o[c] = (short)f2bf(fmaxf(aR[r][c], 0.f));                            \
        const int row = trow + r;                                              \
        *(bf16x8*)&As[buf][(row * 128 + swzb(row, tcol * 2)) >> 1] = o;        \
      }                                                                        \
    }                                                                          \
    /* B: W2[k][n] -> Bs[n][k] bf16, 8k x 4n micro-transpose in regs */        \
    {                                                                          \
      float v[4][8];                                                           \
      _Pragma("unroll")                                                        \
      for (int i = 0; i < 8; ++i) {                                            \
        const float* wrp = &W2[(size_t)(c0 + bkr + i) * HID + bn + bnc];       \
        v[0][i] = wrp[0];  v[1][i] = wrp[32];                                  \
        v[2][i] = wrp[64]; v[3][i] = wrp[96];                                  \
      }                                                                        \
      _Pragma("unroll")                                                        \
      for (int q = 0; q < 4; ++q) {                                            \
        bf16x8 o;                                                              \
        _Pragma("unroll")                                                      \
        for (int i = 0; i < 8; ++i) o[i] = (short)f2bf(v[q][i]);               \
        const int n = q * 32 + bnc;                                            \
        *(bf16x8*)&Bs[buf][(n * 128 + swzb(n, bkr * 2)) >> 1] = o;             \
      }                                                                        \
    }                                                                          \
  }

#define COMPUTE(buf)                                                           \
  {                                                                            \
    _Pragma("unroll")                                                          \
    for (int kk = 0; kk < 2; ++kk) {                                           \
      bf16x8 af[4], bff[4];                                                    \
      _Pragma("unroll")                                                        \
      for (int mi = 0; mi < 4; ++mi) {                                         \
        const int row = wr * 64 + mi * 16 + l15;                               \
        af[mi] = *(const bf16x8*)&As[buf][(row * 128 + swzb(row, kk * 64 + lhi * 16)) >> 1]; \
      }                                                                        \
      _Pragma("unroll")                                                        \
      for (int ni = 0; ni < 4; ++ni) {                                         \
        const int rn = wc * 64 + ni * 16 + l15;                                \
        bff[ni] = *(const bf16x8*)&Bs[buf][(rn * 128 + swzb(rn, kk * 64 + lhi * 16)) >> 1]; \
      }                                                                        \
      _Pragma("unroll")                                                        \
      for (int mi = 0; mi < 4; ++mi)                                           \
        _Pragma("unroll")                                                      \
        for (int ni = 0; ni < 4; ++ni)                                         \
          acc[mi][ni] = __builtin_amdgcn_mfma_f32_16x16x32_bf16(af[mi], bff[ni], acc[mi][ni], 0, 0, 0); \
    }                                                                          \
  }

  PRODUCE(0, 0)
  __syncthreads();
#pragma unroll 1
  for (int kt = 0; kt < 8; ++kt) {
    if (kt < 7) PRODUCE((kt + 1) & 1, kt + 1)
    COMPUTE(kt & 1)
    __syncthreads();   // buf(kt) reads done; buf(kt+1) writes visible
  }

  // ---- epilogue: bias+relu, head partials, 16-lane reduce, wc-combine ----
  // comb[2][128][8] aliases Bs[0] (dead after the final barrier).
  float* combp = (float*)(&Bs[0][0]);
  float bias[4], ws0[4], ws1[4], ws2[4], wa0[4], wa1[4], wc0[4], wc1[4];
#pragma unroll
  for (int ni = 0; ni < 4; ++ni) {
    const int col = bn + wc * 64 + ni * 16 + l15;
    bias[ni] = b2[col];
    ws0[ni] = Wss[col * 3 + 0]; ws1[ni] = Wss[col * 3 + 1]; ws2[ni] = Wss[col * 3 + 2];
    wa0[ni] = Wang[col * 2 + 0]; wa1[ni] = Wang[col * 2 + 1];
    wc0[ni] = Wc[col]; wc1[ni] = Wc[HID + col];
  }
#pragma unroll
  for (int mi = 0; mi < 4; ++mi) {
#pragma unroll
    for (int j = 0; j < 4; ++j) {
      float p0 = 0, p1 = 0, p2 = 0, p3 = 0, p4 = 0, p5 = 0, p6 = 0;
#pragma unroll
      for (int ni = 0; ni < 4; ++ni) {
        const float v = fmaxf(acc[mi][ni][j] + bias[ni], 0.f);
        p0 += v * ws0[ni]; p1 += v * ws1[ni]; p2 += v * ws2[ni];
        p3 += v * wa0[ni]; p4 += v * wa1[ni];
        p5 += v * wc0[ni]; p6 += v * wc1[ni];
      }
#pragma unroll
      for (int m = 1; m <= 8; m <<= 1) {
        p0 += __shfl_xor(p0, m); p1 += __shfl_xor(p1, m); p2 += __shfl_xor(p2, m);
        p3 += __shfl_xor(p3, m); p4 += __shfl_xor(p4, m);
        p5 += __shfl_xor(p5, m); p6 += __shfl_xor(p6, m);
      }
      if (l15 == 0) {
        const int lr = wr * 64 + mi * 16 + lhi * 4 + j;   // local row 0..127
        float* cp = &combp[((size_t)wc * GBM + lr) * 8];
        cp[0] = p0; cp[1] = p1; cp[2] = p2; cp[3] = p3;
        cp[4] = p4; cp[5] = p5; cp[6] = p6;
      }
    }
  }
  __syncthreads();
  if (t < GBM) {
#pragma unroll
    for (int q = 0; q < 7; ++q) {
      const float val = combp[(size_t)t * 8 + q] + combp[((size_t)GBM + t) * 8 + q];
      Hpart[((size_t)(xblk * 7 + q)) * MROWS + bm + t] = val;   // coalesced
    }
  }
#undef PRODUCE
#undef COMPUTE
}

// ===========================================================================
// Kernel 2: finalize + contact. Grid 1024 = 4 batches x 256 tiles of 8 rows.
// cj plane reads are CONTIGUOUS (plane layout), float4-coalesced.
// ===========================================================================
__global__ __launch_bounds__(256) void k_fc(const float* __restrict__ Hpart,
                                            const float* __restrict__ bss,
                                            const float* __restrict__ bang,
                                            const float* __restrict__ bc,
                                            float* __restrict__ ssO,
                                            float* __restrict__ angO,
                                            float* __restrict__ contact) {
  __shared__ float cj_l[LSEQ];
  __shared__ float ci_l[8];
  const int blk = blockIdx.x;
  const int b   = blk >> 8;
  const int i0  = (blk & 255) * 8;
  const int t   = threadIdx.x;
  const size_t rowbase = (size_t)b * LSEQ;

  {
    const float* p0 = Hpart + (size_t)(0 * 7 + 6) * MROWS + rowbase;
    const float* p1 = Hpart + (size_t)(1 * 7 + 6) * MROWS + rowbase;
    const float* p2 = Hpart + (size_t)(2 * 7 + 6) * MROWS + rowbase;
    const float* p3 = Hpart + (size_t)(3 * 7 + 6) * MROWS + rowbase;
#pragma unroll
    for (int it = 0; it < 2; ++it) {
      const int j = it * 1024 + t * 4;
      const float4 a = *(const float4*)&p0[j];
      const float4 bq = *(const float4*)&p1[j];
      const float4 c = *(const float4*)&p2[j];
      const float4 d = *(const float4*)&p3[j];
      float4 s;
      s.x = a.x + bq.x + c.x + d.x;
      s.y = a.y + bq.y + c.y + d.y;
      s.z = a.z + bq.z + c.z + d.z;
      s.w = a.w + bq.w + c.w + d.w;
      *(float4*)&cj_l[j] = s;
    }
  }
  if (t < 8) {
    const size_t r = rowbase + i0 + t;
    float q[6] = {0, 0, 0, 0, 0, 0};
#pragma unroll
    for (int s = 0; s < 4; ++s)
#pragma unroll
      for (int qq = 0; qq < 6; ++qq)
        q[qq] += Hpart[(size_t)(s * 7 + qq) * MROWS + r];
    const float l0 = q[0] + bss[0], l1 = q[1] + bss[1], l2 = q[2] + bss[2];
    const float mx = fmaxf(l0, fmaxf(l1, l2));
    const float e0 = __expf(l0 - mx), e1 = __expf(l1 - mx), e2 = __expf(l2 - mx);
    const float inv = 1.f / (e0 + e1 + e2);
    ssO[r * 3 + 0] = e0 * inv;
    ssO[r * 3 + 1] = e1 * inv;
    ssO[r * 3 + 2] = e2 * inv;
    angO[r * 2 + 0] = q[3] + bang[0];
    angO[r * 2 + 1] = q[4] + bang[1];
    ci_l[t] = q[5] + bc[0];
  }
  __syncthreads();

#pragma unroll
  for (int r = 0; r < 8; ++r) {
    const float base = ci_l[r];
    float* orow = contact + (rowbase + i0 + r) * LSEQ;
#pragma unroll
    for (int jc = 0; jc < 2; ++jc) {
      const int j0 = jc * 1024 + t * 4;
      const float4 c4 = *(const float4*)&cj_l[j0];
      float4 o;
      o.x = 1.f / (1.f + __expf(-(base + c4.x)));
      o.y = 1.f / (1.f + __expf(-(base + c4.y)));
      o.z = 1.f / (1.f + __expf(-(base + c4.z)));
      o.w = 1.f / (1.f + __expf(-(base + c4.w)));
      *(float4*)&orow[j0] = o;
    }
  }
}

// ---------------------------------------------------------------------------
extern "C" void kernel_launch(void* const* d_in, const int* in_sizes, int n_in,
                              void* d_out, int out_size, void* d_ws, size_t ws_size,
                              hipStream_t stream) {
  const float* X    = (const float*)d_in[0];
  const float* W1   = (const float*)d_in[1];
  const float* b1   = (const float*)d_in[2];
  const float* W2   = (const float*)d_in[3];
  const float* b2   = (const float*)d_in[4];
  const float* Wss  = (const float*)d_in[5];
  const float* bss  = (const float*)d_in[6];
  const float* Wang = (const float*)d_in[7];
  const float* bang = (const float*)d_in[8];
  const float* Wc   = (const float*)d_in[9];
  const float* bc   = (const float*)d_in[10];

  float* out     = (float*)d_out;
  float* ssO     = out;                         // [8192,3]
  float* angO    = out + 24576;                 // [8192,2]
  float* contact = out + 40960;                 // [4,2048,2048]

  float* Hpart = (float*)d_ws;                  // [4][7][8192] = 896 KB

  k_gemm_all<<<256, 256, 0, stream>>>(X, W1, b1, W2, b2, Wss, Wang, Wc, Hpart);
  k_fc<<<1024, 256, 0, stream>>>(Hpart, bss, bang, bc, ssO, angO, contact);
}